// Round 1
// baseline (456.658 us; speedup 1.0000x reference)
//
#include <hip/hip_runtime.h>
#include <hip/hip_bf16.h>

#define N_B 4
#define SEQ 2048
#define EMB 1024
#define NH  16
#define HD  64

typedef __attribute__((ext_vector_type(8))) short bf16x8;   // 8 bf16 in 4 VGPRs
typedef __attribute__((ext_vector_type(4))) float f32x4;
typedef unsigned int u32;
typedef unsigned long long u64;
typedef unsigned short u16;

__device__ __forceinline__ void load_lds_16B(const void* g, void* lds) {
  // async global->LDS, 16B per lane; LDS dest = wave-uniform base + lane*16
  __builtin_amdgcn_global_load_lds(
      (const __attribute__((address_space(1))) u32*)g,
      (__attribute__((address_space(3))) u32*)lds, 16, 0, 0);
}

// ---------------- mask -> bitmask (1 uint64 per 64 keys) ----------------
__global__ __launch_bounds__(256) void pack_mask_k(const int* __restrict__ mask,
                                                   u64* __restrict__ bits) {
  int row = blockIdx.x;                // n*SEQ + q
  int lane = threadIdx.x & 63;
  int wv = threadIdx.x >> 6;
  const int* m = mask + (size_t)row * SEQ;
  u64* b = bits + (size_t)row * (SEQ / 64);
  for (int w = wv; w < SEQ / 64; w += 4) {
    int v = m[w * 64 + lane];
    u64 bal = __ballot(v != 0);
    if (lane == 0) b[w] = bal;
  }
}

// ---------------- per-head projection: out[n][h][l][d] = sum_d' x[n][l][h*64+d'] W[d][d'] ----
__global__ __launch_bounds__(256) void project_k(const float* __restrict__ x,
                                                 const float* __restrict__ W,
                                                 __hip_bfloat16* __restrict__ out) {
  __shared__ float Ws[64 * 65];   // +1 pad: conflict-free
  __shared__ float xs[1024];
  int t = threadIdx.x;
  int row = blockIdx.x;            // n*SEQ + l
  int n = row >> 11, l = row & 2047;
#pragma unroll
  for (int i = 0; i < 16; ++i) {
    int idx = i * 256 + t;
    Ws[(idx >> 6) * 65 + (idx & 63)] = W[idx];
  }
  const float4* x4 = (const float4*)(x + (size_t)row * EMB);
  float4 v = x4[t];
  xs[t * 4 + 0] = v.x; xs[t * 4 + 1] = v.y;
  xs[t * 4 + 2] = v.z; xs[t * 4 + 3] = v.w;
  __syncthreads();
#pragma unroll
  for (int i = 0; i < 4; ++i) {
    int oidx = i * 256 + t;
    int h = oidx >> 6, d = oidx & 63;
    const float* xr = &xs[h * 64];
    const float* wr = &Ws[d * 65];
    float s = 0.f;
#pragma unroll
    for (int dd = 0; dd < 64; ++dd) s += xr[dd] * wr[dd];
    out[((size_t)(n * NH + h) * SEQ + l) * HD + d] = __float2bfloat16(s);
  }
}

// ---------------- fp32 -> bf16 copy (Wo) ----------------
__global__ __launch_bounds__(256) void cvt_bf16_k(const float* __restrict__ in,
                                                  __hip_bfloat16* __restrict__ out) {
  int i = (blockIdx.x * 256 + threadIdx.x) * 4;
  float4 v = *(const float4*)(in + i);
  out[i + 0] = __float2bfloat16(v.x);
  out[i + 1] = __float2bfloat16(v.y);
  out[i + 2] = __float2bfloat16(v.z);
  out[i + 3] = __float2bfloat16(v.w);
}

// ---------------- flash attention ----------------
// grid: (SEQ/64, N_B*NH), 256 thr (4 waves). Wave w owns q-rows [w*16, w*16+16).
__global__ __launch_bounds__(256) void attn_k(const __hip_bfloat16* __restrict__ qp,
                                              const __hip_bfloat16* __restrict__ kp,
                                              const __hip_bfloat16* __restrict__ vp,
                                              const u64* __restrict__ mbits,
                                              __hip_bfloat16* __restrict__ obuf) {
  __shared__ __align__(16) __hip_bfloat16 Kt[64 * 64];       // [key][d] linear
  __shared__ __align__(16) __hip_bfloat16 Vt[64 * 72];       // [d][key] pad->72
  __shared__ __align__(16) __hip_bfloat16 Pl[4][16 * 64];    // per-wave P strip
  int t = threadIdx.x, lane = t & 63, w = t >> 6;
  int qb = blockIdx.x;
  int nh = blockIdx.y;
  int n = nh >> 4, h = nh & 15;
  const __hip_bfloat16* Qg = qp + ((size_t)nh * SEQ + qb * 64) * HD;
  const __hip_bfloat16* Kg = kp + (size_t)nh * SEQ * HD;
  const __hip_bfloat16* Vg = vp + (size_t)nh * SEQ * HD;
  int l15 = lane & 15, l4 = lane >> 4;

  // Q fragments, held in regs for whole kernel. A-frag: row=lane&15, k=(lane>>4)*8+j
  bf16x8 qf[2];
#pragma unroll
  for (int c = 0; c < 2; ++c)
    qf[c] = *(const bf16x8*)(Qg + (size_t)(w * 16 + l15) * HD + c * 32 + l4 * 8);

  f32x4 of[4];
#pragma unroll
  for (int dt = 0; dt < 4; ++dt)
#pragma unroll
    for (int j = 0; j < 4; ++j) of[dt][j] = 0.f;
  float mrow[4], lrow[4];
#pragma unroll
  for (int r = 0; r < 4; ++r) { mrow[r] = -1e20f; lrow[r] = 0.f; }

  const u64* mrow_base = mbits + ((size_t)n * SEQ + qb * 64 + w * 16 + l4 * 4) * (SEQ / 64);

  for (int kt = 0; kt < SEQ / 64; ++kt) {
    __syncthreads();   // previous iteration's LDS reads complete
    // ---- stage K tile (linear [64][64])
    {
      const char* g = (const char*)(Kg + (size_t)kt * 64 * HD) + t * 16;
      char* ldsb = (char*)Kt + w * 1024;
      load_lds_16B(g, ldsb);
      load_lds_16B(g + 4096, ldsb + 4096);
    }
    // ---- stage V transposed: Vt[d][key]; coalesced global reads (lane=d)
    {
      const __hip_bfloat16* vg = Vg + (size_t)kt * 64 * HD;
#pragma unroll
      for (int i = 0; i < 2; ++i) {
        int d = lane;
        int kc = w * 2 + i;                 // key chunk 0..7
        union { u16 s[8]; uint4 v4; } u;
#pragma unroll
        for (int j = 0; j < 8; ++j)
          u.s[j] = *(const u16*)(vg + (size_t)(kc * 8 + j) * HD + d);
        *(uint4*)((char*)Vt + d * 144 + kc * 16) = u.v4;
      }
    }
    asm volatile("s_waitcnt vmcnt(0)" ::: "memory");
    __syncthreads();

    // ---- S = Q K^T  (wave strip 16x64)
    f32x4 sf[4];
#pragma unroll
    for (int ct = 0; ct < 4; ++ct)
#pragma unroll
      for (int j = 0; j < 4; ++j) sf[ct][j] = 0.f;
#pragma unroll
    for (int c = 0; c < 2; ++c) {
#pragma unroll
      for (int ct = 0; ct < 4; ++ct) {
        bf16x8 bk = *(const bf16x8*)((const char*)Kt + (ct * 16 + l15) * 128 + c * 64 + l4 * 16);
        sf[ct] = __builtin_amdgcn_mfma_f32_16x16x32_bf16(qf[c], bk, sf[ct], 0, 0, 0);
      }
    }
    // ---- scale + mask + online softmax (C layout: col=lane&15, row=l4*4+reg)
    u64 mw[4];
#pragma unroll
    for (int r = 0; r < 4; ++r) mw[r] = mrow_base[(size_t)r * (SEQ / 64) + kt];
    float tmax[4];
#pragma unroll
    for (int r = 0; r < 4; ++r) tmax[r] = -1e20f;
#pragma unroll
    for (int ct = 0; ct < 4; ++ct) {
#pragma unroll
      for (int r = 0; r < 4; ++r) {
        float v = sf[ct][r] * 0.03125f;
        if (!((mw[r] >> (ct * 16 + l15)) & 1)) v = -1e20f;
        sf[ct][r] = v;
        tmax[r] = fmaxf(tmax[r], v);
      }
    }
#pragma unroll
    for (int off = 1; off < 16; off <<= 1)
#pragma unroll
      for (int r = 0; r < 4; ++r)
        tmax[r] = fmaxf(tmax[r], __shfl_xor(tmax[r], off, 16));
    float corr[4], rsum[4];
#pragma unroll
    for (int r = 0; r < 4; ++r) {
      float mn = fmaxf(mrow[r], tmax[r]);
      corr[r] = __expf(mrow[r] - mn);
      mrow[r] = mn;
      float rs = 0.f;
#pragma unroll
      for (int ct = 0; ct < 4; ++ct) {
        float p = __expf(sf[ct][r] - mn);
        sf[ct][r] = p;
        rs += p;
      }
      rsum[r] = rs;
    }
#pragma unroll
    for (int off = 1; off < 16; off <<= 1)
#pragma unroll
      for (int r = 0; r < 4; ++r)
        rsum[r] += __shfl_xor(rsum[r], off, 16);
#pragma unroll
    for (int r = 0; r < 4; ++r) lrow[r] = lrow[r] * corr[r] + rsum[r];
#pragma unroll
    for (int dt = 0; dt < 4; ++dt)
#pragma unroll
      for (int r = 0; r < 4; ++r) of[dt][r] *= corr[r];
    // ---- P -> LDS (per-wave strip), then PV
#pragma unroll
    for (int ct = 0; ct < 4; ++ct)
#pragma unroll
      for (int r = 0; r < 4; ++r)
        Pl[w][(l4 * 4 + r) * 64 + ct * 16 + l15] = __float2bfloat16(sf[ct][r]);
#pragma unroll
    for (int kc = 0; kc < 2; ++kc) {
      bf16x8 pa = *(const bf16x8*)((const char*)&Pl[w][0] + l15 * 128 + kc * 64 + l4 * 16);
#pragma unroll
      for (int dt = 0; dt < 4; ++dt) {
        bf16x8 bv = *(const bf16x8*)((const char*)Vt + (dt * 16 + l15) * 144 + kc * 64 + l4 * 16);
        of[dt] = __builtin_amdgcn_mfma_f32_16x16x32_bf16(pa, bv, of[dt], 0, 0, 0);
      }
    }
  }
  // ---- epilogue: O /= l, write [n*SEQ+q][h*64+d] bf16
#pragma unroll
  for (int r = 0; r < 4; ++r) lrow[r] = 1.f / lrow[r];
  size_t orow0 = (size_t)n * SEQ + qb * 64 + w * 16 + l4 * 4;
#pragma unroll
  for (int dt = 0; dt < 4; ++dt)
#pragma unroll
    for (int r = 0; r < 4; ++r) {
      float v = of[dt][r] * lrow[r];
      obuf[(orow0 + r) * EMB + h * HD + dt * 16 + l15] = __float2bfloat16(v);
    }
}

// ---------------- output GEMM: Y[8192][1024] = A @ Wo^T + bo (fp32 out) ----------------
__global__ __launch_bounds__(256) void out_gemm_k(const __hip_bfloat16* __restrict__ A,
                                                  const __hip_bfloat16* __restrict__ Bw,
                                                  const float* __restrict__ bias,
                                                  float* __restrict__ Y) {
  __shared__ __align__(16) __hip_bfloat16 As[128 * 32];
  __shared__ __align__(16) __hip_bfloat16 Bs[128 * 32];
  int t = threadIdx.x, lane = t & 63, w = t >> 6;
  int l15 = lane & 15, l4 = lane >> 4;
  int bm = blockIdx.x * 128, bn = blockIdx.y * 128;
  int wr = w >> 1, wc = w & 1;
  f32x4 acc[4][4];
#pragma unroll
  for (int m = 0; m < 4; ++m)
#pragma unroll
    for (int nn = 0; nn < 4; ++nn)
#pragma unroll
      for (int j = 0; j < 4; ++j) acc[m][nn][j] = 0.f;

  int o = t * 8;
  int srow = o >> 5, scol = o & 31;
  for (int kt = 0; kt < 32; ++kt) {
    __syncthreads();
    {
      const char* ga = (const char*)(A + (size_t)(bm + srow) * 1024 + kt * 32 + scol);
      char* la = (char*)As + w * 1024;
      load_lds_16B(ga, la);
      load_lds_16B((const char*)(A + (size_t)(bm + srow + 64) * 1024 + kt * 32 + scol), la + 4096);
      const char* gb = (const char*)(Bw + (size_t)(bn + srow) * 1024 + kt * 32 + scol);
      char* lb = (char*)Bs + w * 1024;
      load_lds_16B(gb, lb);
      load_lds_16B((const char*)(Bw + (size_t)(bn + srow + 64) * 1024 + kt * 32 + scol), lb + 4096);
    }
    asm volatile("s_waitcnt vmcnt(0)" ::: "memory");
    __syncthreads();
    bf16x8 af[4], bfr[4];
#pragma unroll
    for (int m = 0; m < 4; ++m)
      af[m] = *(const bf16x8*)((const char*)As + (wr * 64 + m * 16 + l15) * 64 + l4 * 16);
#pragma unroll
    for (int nn = 0; nn < 4; ++nn)
      bfr[nn] = *(const bf16x8*)((const char*)Bs + (wc * 64 + nn * 16 + l15) * 64 + l4 * 16);
#pragma unroll
    for (int m = 0; m < 4; ++m)
#pragma unroll
      for (int nn = 0; nn < 4; ++nn)
        acc[m][nn] = __builtin_amdgcn_mfma_f32_16x16x32_bf16(af[m], bfr[nn], acc[m][nn], 0, 0, 0);
  }
#pragma unroll
  for (int m = 0; m < 4; ++m)
#pragma unroll
    for (int nn = 0; nn < 4; ++nn)
#pragma unroll
      for (int r = 0; r < 4; ++r) {
        int row = bm + wr * 64 + m * 16 + l4 * 4 + r;
        int col = bn + wc * 64 + nn * 16 + l15;
        Y[(size_t)row * 1024 + col] = acc[m][nn][r] + bias[col];
      }
}

extern "C" void kernel_launch(void* const* d_in, const int* in_sizes, int n_in,
                              void* d_out, int out_size, void* d_ws, size_t ws_size,
                              hipStream_t stream) {
  const float* values  = (const float*)d_in[0];
  const float* keys    = (const float*)d_in[1];
  const float* queries = (const float*)d_in[2];
  const int*   mask    = (const int*)d_in[3];
  const float* Wv      = (const float*)d_in[4];
  const float* Wk      = (const float*)d_in[5];
  const float* Wq      = (const float*)d_in[6];
  const float* Wo      = (const float*)d_in[7];
  const float* bo      = (const float*)d_in[8];
  float* out = (float*)d_out;

  char* ws = (char*)d_ws;
  __hip_bfloat16* qp   = (__hip_bfloat16*)(ws);
  __hip_bfloat16* kp   = (__hip_bfloat16*)(ws + (size_t)16 * 1024 * 1024);
  __hip_bfloat16* vp   = (__hip_bfloat16*)(ws + (size_t)32 * 1024 * 1024);
  __hip_bfloat16* obuf = (__hip_bfloat16*)(ws + (size_t)48 * 1024 * 1024);
  u64*            mbts = (u64*)           (ws + (size_t)64 * 1024 * 1024);
  __hip_bfloat16* wob  = (__hip_bfloat16*)(ws + (size_t)66 * 1024 * 1024);

  pack_mask_k<<<dim3(N_B * SEQ), 256, 0, stream>>>(mask, mbts);
  project_k<<<dim3(N_B * SEQ), 256, 0, stream>>>(queries, Wq, qp);
  project_k<<<dim3(N_B * SEQ), 256, 0, stream>>>(keys, Wk, kp);
  project_k<<<dim3(N_B * SEQ), 256, 0, stream>>>(values, Wv, vp);
  cvt_bf16_k<<<dim3(1024), 256, 0, stream>>>(Wo, wob);
  attn_k<<<dim3(SEQ / 64, N_B * NH), 256, 0, stream>>>(qp, kp, vp, mbts, obuf);
  out_gemm_k<<<dim3(64, 8), 256, 0, stream>>>(obuf, wob, bo, out);
}

// Round 2
// 356.917 us; speedup vs baseline: 1.2795x; 1.2795x over previous
//
#include <hip/hip_runtime.h>
#include <hip/hip_bf16.h>

#define N_B 4
#define SEQ 2048
#define EMB 1024
#define NH  16
#define HD  64

typedef __attribute__((ext_vector_type(8))) short bf16x8;   // 8 bf16 in 4 VGPRs
typedef __attribute__((ext_vector_type(4))) float f32x4;
typedef unsigned int u32;
typedef unsigned long long u64;
typedef unsigned short u16;

__device__ __forceinline__ void load_lds_16B(const void* g, void* lds) {
  __builtin_amdgcn_global_load_lds(
      (const __attribute__((address_space(1))) u32*)g,
      (__attribute__((address_space(3))) u32*)lds, 16, 0, 0);
}

// ---------------- mask -> bitmask (1 uint64 per 64 keys) ----------------
__global__ __launch_bounds__(256) void pack_mask_k(const int* __restrict__ mask,
                                                   u64* __restrict__ bits) {
  int row = blockIdx.x;                // n*SEQ + q
  int lane = threadIdx.x & 63;
  int wv = threadIdx.x >> 6;
  const int* m = mask + (size_t)row * SEQ;
  u64* b = bits + (size_t)row * (SEQ / 64);
  for (int w = wv; w < SEQ / 64; w += 4) {
    int v = m[w * 64 + lane];
    u64 bal = __ballot(v != 0);
    if (lane == 0) b[w] = bal;
  }
}

// ---------------- per-head projection ----------------
__global__ __launch_bounds__(256) void project_k(const float* __restrict__ x,
                                                 const float* __restrict__ W,
                                                 __hip_bfloat16* __restrict__ out) {
  __shared__ __align__(16) float Ws4[64 * 17 * 4];  // W rows as float4, padded: [d][17]
  __shared__ __align__(16) float xs[1024];
  int t = threadIdx.x;
  int row = blockIdx.x;            // n*SEQ + l
  int n = row >> 11, l = row & 2047;
  const float4* W4 = (const float4*)W;
#pragma unroll
  for (int i = 0; i < 4; ++i) {
    int f4 = i * 256 + t;                 // f4 = d*16 + dd4
    int d = f4 >> 4, dd4 = f4 & 15;
    *(float4*)&Ws4[(d * 17 + dd4) * 4] = W4[f4];
  }
  float4 v = ((const float4*)(x + (size_t)row * EMB))[t];
  *(float4*)&xs[t * 4] = v;
  __syncthreads();
  int d = t & 63, wv = t >> 6;
  float s[4] = {0.f, 0.f, 0.f, 0.f};
#pragma unroll
  for (int dd4 = 0; dd4 < 16; ++dd4) {
    float4 wv4 = *(const float4*)&Ws4[(d * 17 + dd4) * 4];
#pragma unroll
    for (int i = 0; i < 4; ++i) {
      float4 xv = *(const float4*)&xs[(i * 4 + wv) * 64 + dd4 * 4];
      s[i] += xv.x * wv4.x + xv.y * wv4.y + xv.z * wv4.z + xv.w * wv4.w;
    }
  }
#pragma unroll
  for (int i = 0; i < 4; ++i) {
    int h = i * 4 + wv;
    out[((size_t)(n * NH + h) * SEQ + l) * HD + d] = __float2bfloat16(s[i]);
  }
}

// ---------------- fp32 -> bf16 copy (Wo) ----------------
__global__ __launch_bounds__(256) void cvt_bf16_k(const float* __restrict__ in,
                                                  __hip_bfloat16* __restrict__ out) {
  int i = (blockIdx.x * 256 + threadIdx.x) * 4;
  float4 v = *(const float4*)(in + i);
  out[i + 0] = __float2bfloat16(v.x);
  out[i + 1] = __float2bfloat16(v.y);
  out[i + 2] = __float2bfloat16(v.z);
  out[i + 3] = __float2bfloat16(v.w);
}

// ---------------- V transpose: vp[nh][key][d] -> vT[nh][d][key] ----------------
__global__ __launch_bounds__(256) void transpose_v_k(const __hip_bfloat16* __restrict__ vp,
                                                     __hip_bfloat16* __restrict__ vT) {
  __shared__ __align__(16) u16 Ls[64 * 64];   // [key][d], XOR-swizzled 16B chunks
  int t = threadIdx.x;
  int kt = blockIdx.x, nh = blockIdx.y;
  const u16* src = (const u16*)(vp + ((size_t)nh * SEQ + kt * 64) * HD);
#pragma unroll
  for (int p = 0; p < 2; ++p) {
    int key = p * 32 + (t >> 3);
    int dc = t & 7;                         // 16B chunk within row
    uint4 vv = *(const uint4*)(src + key * 64 + dc * 8);
    *(uint4*)((char*)Ls + key * 128 + ((dc ^ (key & 7)) * 16)) = vv;
  }
  __syncthreads();
  u16* dst = (u16*)(vT + (size_t)nh * HD * SEQ);
#pragma unroll
  for (int p = 0; p < 2; ++p) {
    int d = p * 32 + (t >> 3);
    int kc = t & 7;                         // key chunk (8 keys)
    union { u16 s[8]; uint4 v4; } u;
#pragma unroll
    for (int j = 0; j < 8; ++j) {
      int key = kc * 8 + j;
      u.s[j] = *(const u16*)((const char*)Ls + key * 128 + (((d >> 3) ^ (key & 7)) * 16) + (d & 7) * 2);
    }
    *(uint4*)(dst + (size_t)d * SEQ + kt * 64 + kc * 8) = u.v4;
  }
}

// ---------------- flash attention ----------------
__global__ __launch_bounds__(256) void attn_k(const __hip_bfloat16* __restrict__ qp,
                                              const __hip_bfloat16* __restrict__ kp,
                                              const __hip_bfloat16* __restrict__ vT,
                                              const u64* __restrict__ mbits,
                                              __hip_bfloat16* __restrict__ obuf) {
  __shared__ __align__(16) __hip_bfloat16 Kt[64 * 64];       // [key][kdim] swizzled
  __shared__ __align__(16) __hip_bfloat16 Vt[64 * 64];       // [d][key]   swizzled
  __shared__ __align__(16) __hip_bfloat16 Pl[4][16 * 64];    // per-wave P strip, swizzled
  int t = threadIdx.x, lane = t & 63, w = t >> 6;
  int qb = blockIdx.x;
  int nh = blockIdx.y;
  int n = nh >> 4, h = nh & 15;
  const __hip_bfloat16* Qg = qp + ((size_t)nh * SEQ + qb * 64) * HD;
  const char* Kg = (const char*)(kp + (size_t)nh * SEQ * HD);
  const char* Vg = (const char*)(vT + (size_t)nh * HD * SEQ);
  int l15 = lane & 15, l4 = lane >> 4;

  int srow = t >> 3;
  int schunk = (t & 7) ^ (srow & 7);
  int soffA = srow * 128 + schunk * 16;

  bf16x8 qf[2];
#pragma unroll
  for (int c = 0; c < 2; ++c)
    qf[c] = *(const bf16x8*)(Qg + (size_t)(w * 16 + l15) * HD + c * 32 + l4 * 8);

  f32x4 of[4];
#pragma unroll
  for (int dt = 0; dt < 4; ++dt)
#pragma unroll
    for (int j = 0; j < 4; ++j) of[dt][j] = 0.f;
  float mrow[4], lrow[4];
#pragma unroll
  for (int r = 0; r < 4; ++r) { mrow[r] = -1e20f; lrow[r] = 0.f; }

  const u64* mrow_base = mbits + ((size_t)n * SEQ + qb * 64 + w * 16 + l4 * 4) * (SEQ / 64);

  for (int kt = 0; kt < SEQ / 64; ++kt) {
    __syncthreads();
    {
      const char* gk = Kg + (size_t)kt * 8192;
      char* lk = (char*)Kt + w * 1024;
      load_lds_16B(gk + soffA, lk);
      load_lds_16B(gk + soffA + 4096, lk + 4096);   // rows+32: same XOR since (r+32)&7==r&7
      const char* gv = Vg + (size_t)kt * 128;
      char* lv = (char*)Vt + w * 1024;
      load_lds_16B(gv + (size_t)srow * 4096 + (size_t)schunk * 16, lv);
      load_lds_16B(gv + (size_t)(srow + 32) * 4096 + (size_t)schunk * 16, lv + 4096);
    }
    asm volatile("s_waitcnt vmcnt(0)" ::: "memory");
    __syncthreads();

    f32x4 sf[4];
#pragma unroll
    for (int ct = 0; ct < 4; ++ct)
#pragma unroll
      for (int j = 0; j < 4; ++j) sf[ct][j] = 0.f;
#pragma unroll
    for (int c = 0; c < 2; ++c) {
#pragma unroll
      for (int ct = 0; ct < 4; ++ct) {
        int krow = ct * 16 + l15;
        bf16x8 bk = *(const bf16x8*)((const char*)Kt + krow * 128 + (((c * 4 + l4) ^ (l15 & 7)) * 16));
        sf[ct] = __builtin_amdgcn_mfma_f32_16x16x32_bf16(qf[c], bk, sf[ct], 0, 0, 0);
      }
    }
    u64 mw[4];
#pragma unroll
    for (int r = 0; r < 4; ++r) mw[r] = mrow_base[(size_t)r * (SEQ / 64) + kt];
    float tmax[4];
#pragma unroll
    for (int r = 0; r < 4; ++r) tmax[r] = -1e20f;
#pragma unroll
    for (int ct = 0; ct < 4; ++ct) {
#pragma unroll
      for (int r = 0; r < 4; ++r) {
        float v = sf[ct][r] * 0.03125f;
        if (!((mw[r] >> (ct * 16 + l15)) & 1)) v = -1e20f;
        sf[ct][r] = v;
        tmax[r] = fmaxf(tmax[r], v);
      }
    }
#pragma unroll
    for (int off = 1; off < 16; off <<= 1)
#pragma unroll
      for (int r = 0; r < 4; ++r)
        tmax[r] = fmaxf(tmax[r], __shfl_xor(tmax[r], off, 16));
    float corr[4], rsum[4];
#pragma unroll
    for (int r = 0; r < 4; ++r) {
      float mn = fmaxf(mrow[r], tmax[r]);
      corr[r] = __expf(mrow[r] - mn);
      mrow[r] = mn;
      float rs = 0.f;
#pragma unroll
      for (int ct = 0; ct < 4; ++ct) {
        float p = __expf(sf[ct][r] - mn);
        sf[ct][r] = p;
        rs += p;
      }
      rsum[r] = rs;
    }
#pragma unroll
    for (int off = 1; off < 16; off <<= 1)
#pragma unroll
      for (int r = 0; r < 4; ++r)
        rsum[r] += __shfl_xor(rsum[r], off, 16);
#pragma unroll
    for (int r = 0; r < 4; ++r) lrow[r] = lrow[r] * corr[r] + rsum[r];
#pragma unroll
    for (int dt = 0; dt < 4; ++dt)
#pragma unroll
      for (int r = 0; r < 4; ++r) of[dt][r] *= corr[r];
#pragma unroll
    for (int ct = 0; ct < 4; ++ct)
#pragma unroll
      for (int r = 0; r < 4; ++r) {
        int prow = l4 * 4 + r;
        int pchunk = (ct * 2 + (l15 >> 3)) ^ (prow & 7);
        *(__hip_bfloat16*)((char*)&Pl[w][0] + prow * 128 + pchunk * 16 + (l15 & 7) * 2) =
            __float2bfloat16(sf[ct][r]);
      }
#pragma unroll
    for (int kc = 0; kc < 2; ++kc) {
      bf16x8 pa = *(const bf16x8*)((const char*)&Pl[w][0] + l15 * 128 + (((kc * 4 + l4) ^ (l15 & 7)) * 16));
#pragma unroll
      for (int dt = 0; dt < 4; ++dt) {
        int vrow = dt * 16 + l15;
        bf16x8 bv = *(const bf16x8*)((const char*)Vt + vrow * 128 + (((kc * 4 + l4) ^ (l15 & 7)) * 16));
        of[dt] = __builtin_amdgcn_mfma_f32_16x16x32_bf16(pa, bv, of[dt], 0, 0, 0);
      }
    }
  }
#pragma unroll
  for (int r = 0; r < 4; ++r) lrow[r] = 1.f / lrow[r];
  size_t orow0 = (size_t)n * SEQ + qb * 64 + w * 16 + l4 * 4;
#pragma unroll
  for (int dt = 0; dt < 4; ++dt)
#pragma unroll
    for (int r = 0; r < 4; ++r) {
      float v = of[dt][r] * lrow[r];
      obuf[(orow0 + r) * EMB + h * HD + dt * 16 + l15] = __float2bfloat16(v);
    }
}

// ---------------- output GEMM ----------------
__global__ __launch_bounds__(256) void out_gemm_k(const __hip_bfloat16* __restrict__ A,
                                                  const __hip_bfloat16* __restrict__ Bw,
                                                  const float* __restrict__ bias,
                                                  float* __restrict__ Y) {
  __shared__ __align__(16) __hip_bfloat16 As[128 * 32];
  __shared__ __align__(16) __hip_bfloat16 Bs[128 * 32];
  int t = threadIdx.x, lane = t & 63, w = t >> 6;
  int l15 = lane & 15, l4 = lane >> 4;
  int bm = blockIdx.x * 128, bn = blockIdx.y * 128;
  int wr = w >> 1, wc = w & 1;
  f32x4 acc[4][4];
#pragma unroll
  for (int m = 0; m < 4; ++m)
#pragma unroll
    for (int nn = 0; nn < 4; ++nn)
#pragma unroll
      for (int j = 0; j < 4; ++j) acc[m][nn][j] = 0.f;

  int o = t * 8;
  int srow = o >> 5, scol = o & 31;
  for (int kt = 0; kt < 32; ++kt) {
    __syncthreads();
    {
      const char* ga = (const char*)(A + (size_t)(bm + srow) * 1024 + kt * 32 + scol);
      char* la = (char*)As + w * 1024;
      load_lds_16B(ga, la);
      load_lds_16B((const char*)(A + (size_t)(bm + srow + 64) * 1024 + kt * 32 + scol), la + 4096);
      const char* gb = (const char*)(Bw + (size_t)(bn + srow) * 1024 + kt * 32 + scol);
      char* lb = (char*)Bs + w * 1024;
      load_lds_16B(gb, lb);
      load_lds_16B((const char*)(Bw + (size_t)(bn + srow + 64) * 1024 + kt * 32 + scol), lb + 4096);
    }
    asm volatile("s_waitcnt vmcnt(0)" ::: "memory");
    __syncthreads();
    bf16x8 af[4], bfr[4];
#pragma unroll
    for (int m = 0; m < 4; ++m)
      af[m] = *(const bf16x8*)((const char*)As + (wr * 64 + m * 16 + l15) * 64 + l4 * 16);
#pragma unroll
    for (int nn = 0; nn < 4; ++nn)
      bfr[nn] = *(const bf16x8*)((const char*)Bs + (wc * 64 + nn * 16 + l15) * 64 + l4 * 16);
#pragma unroll
    for (int m = 0; m < 4; ++m)
#pragma unroll
      for (int nn = 0; nn < 4; ++nn)
        acc[m][nn] = __builtin_amdgcn_mfma_f32_16x16x32_bf16(af[m], bfr[nn], acc[m][nn], 0, 0, 0);
  }
#pragma unroll
  for (int m = 0; m < 4; ++m)
#pragma unroll
    for (int nn = 0; nn < 4; ++nn)
#pragma unroll
      for (int r = 0; r < 4; ++r) {
        int row = bm + wr * 64 + m * 16 + l4 * 4 + r;
        int col = bn + wc * 64 + nn * 16 + l15;
        Y[(size_t)row * 1024 + col] = acc[m][nn][r] + bias[col];
      }
}

extern "C" void kernel_launch(void* const* d_in, const int* in_sizes, int n_in,
                              void* d_out, int out_size, void* d_ws, size_t ws_size,
                              hipStream_t stream) {
  const float* values  = (const float*)d_in[0];
  const float* keys    = (const float*)d_in[1];
  const float* queries = (const float*)d_in[2];
  const int*   mask    = (const int*)d_in[3];
  const float* Wv      = (const float*)d_in[4];
  const float* Wk      = (const float*)d_in[5];
  const float* Wq      = (const float*)d_in[6];
  const float* Wo      = (const float*)d_in[7];
  const float* bo      = (const float*)d_in[8];
  float* out = (float*)d_out;

  char* ws = (char*)d_ws;
  __hip_bfloat16* qp   = (__hip_bfloat16*)(ws);
  __hip_bfloat16* kp   = (__hip_bfloat16*)(ws + (size_t)16 * 1024 * 1024);
  __hip_bfloat16* vp   = (__hip_bfloat16*)(ws + (size_t)32 * 1024 * 1024);
  __hip_bfloat16* obuf = (__hip_bfloat16*)(ws + (size_t)48 * 1024 * 1024);
  u64*            mbts = (u64*)           (ws + (size_t)64 * 1024 * 1024);
  __hip_bfloat16* wob  = (__hip_bfloat16*)(ws + (size_t)66 * 1024 * 1024);
  __hip_bfloat16* vTp  = (__hip_bfloat16*)(ws + (size_t)80 * 1024 * 1024);

  pack_mask_k<<<dim3(N_B * SEQ), 256, 0, stream>>>(mask, mbts);
  project_k<<<dim3(N_B * SEQ), 256, 0, stream>>>(queries, Wq, qp);
  project_k<<<dim3(N_B * SEQ), 256, 0, stream>>>(keys, Wk, kp);
  project_k<<<dim3(N_B * SEQ), 256, 0, stream>>>(values, Wv, vp);
  transpose_v_k<<<dim3(SEQ / 64, N_B * NH), 256, 0, stream>>>(vp, vTp);
  cvt_bf16_k<<<dim3(1024), 256, 0, stream>>>(Wo, wob);
  attn_k<<<dim3(SEQ / 64, N_B * NH), 256, 0, stream>>>(qp, kp, vTp, mbts, obuf);
  out_gemm_k<<<dim3(64, 8), 256, 0, stream>>>(obuf, wob, bo, out);
}

// Round 3
// 325.193 us; speedup vs baseline: 1.4043x; 1.0976x over previous
//
#include <hip/hip_runtime.h>
#include <hip/hip_bf16.h>

#define N_B 4
#define SEQ 2048
#define EMB 1024
#define NH  16
#define HD  64

typedef __attribute__((ext_vector_type(8))) short bf16x8;   // 8 bf16 in 4 VGPRs
typedef __attribute__((ext_vector_type(4))) float f32x4;
typedef unsigned int u32;
typedef unsigned long long u64;
typedef unsigned short u16;

__device__ __forceinline__ void load_lds_16B(const void* g, void* lds) {
  __builtin_amdgcn_global_load_lds(
      (const __attribute__((address_space(1))) u32*)g,
      (__attribute__((address_space(3))) u32*)lds, 16, 0, 0);
}

// ---------------- mask -> bitmask, layout [n][kb][q] (contiguous in q) ----------------
__global__ __launch_bounds__(256) void pack_mask_k(const int* __restrict__ mask,
                                                   u64* __restrict__ bits) {
  int row = blockIdx.x;                // n*SEQ + q
  int n = row >> 11, q = row & 2047;
  int lane = threadIdx.x & 63;
  int wv = threadIdx.x >> 6;
  const int* m = mask + (size_t)row * SEQ;
  for (int w = wv; w < SEQ / 64; w += 4) {
    int v = m[w * 64 + lane];
    u64 bal = __ballot(v != 0);
    if (lane == 0) bits[((size_t)n * 32 + w) * 2048 + q] = bal;
  }
}

// ---------------- per-head projection (optional output scale) ----------------
__global__ __launch_bounds__(256) void project_k(const float* __restrict__ x,
                                                 const float* __restrict__ W,
                                                 __hip_bfloat16* __restrict__ out,
                                                 float scale) {
  __shared__ __align__(16) float Ws4[64 * 17 * 4];  // W rows as float4, padded: [d][17]
  __shared__ __align__(16) float xs[1024];
  int t = threadIdx.x;
  int row = blockIdx.x;            // n*SEQ + l
  int n = row >> 11, l = row & 2047;
  const float4* W4 = (const float4*)W;
#pragma unroll
  for (int i = 0; i < 4; ++i) {
    int f4 = i * 256 + t;                 // f4 = d*16 + dd4
    int d = f4 >> 4, dd4 = f4 & 15;
    *(float4*)&Ws4[(d * 17 + dd4) * 4] = W4[f4];
  }
  float4 v = ((const float4*)(x + (size_t)row * EMB))[t];
  *(float4*)&xs[t * 4] = v;
  __syncthreads();
  int d = t & 63, wv = t >> 6;
  float s[4] = {0.f, 0.f, 0.f, 0.f};
#pragma unroll
  for (int dd4 = 0; dd4 < 16; ++dd4) {
    float4 wv4 = *(const float4*)&Ws4[(d * 17 + dd4) * 4];
#pragma unroll
    for (int i = 0; i < 4; ++i) {
      float4 xv = *(const float4*)&xs[(i * 4 + wv) * 64 + dd4 * 4];
      s[i] += xv.x * wv4.x + xv.y * wv4.y + xv.z * wv4.z + xv.w * wv4.w;
    }
  }
#pragma unroll
  for (int i = 0; i < 4; ++i) {
    int h = i * 4 + wv;
    out[((size_t)(n * NH + h) * SEQ + l) * HD + d] = __float2bfloat16(s[i] * scale);
  }
}

// ---------------- fp32 -> bf16 copy (Wo) ----------------
__global__ __launch_bounds__(256) void cvt_bf16_k(const float* __restrict__ in,
                                                  __hip_bfloat16* __restrict__ out) {
  int i = (blockIdx.x * 256 + threadIdx.x) * 4;
  float4 v = *(const float4*)(in + i);
  out[i + 0] = __float2bfloat16(v.x);
  out[i + 1] = __float2bfloat16(v.y);
  out[i + 2] = __float2bfloat16(v.z);
  out[i + 3] = __float2bfloat16(v.w);
}

// ---------------- V transpose: vp[nh][key][d] -> vT[nh][d][key] ----------------
__global__ __launch_bounds__(256) void transpose_v_k(const __hip_bfloat16* __restrict__ vp,
                                                     __hip_bfloat16* __restrict__ vT) {
  __shared__ __align__(16) u16 Ls[64 * 64];   // [key][d], XOR-swizzled 16B chunks
  int t = threadIdx.x;
  int kt = blockIdx.x, nh = blockIdx.y;
  const u16* src = (const u16*)(vp + ((size_t)nh * SEQ + kt * 64) * HD);
#pragma unroll
  for (int p = 0; p < 2; ++p) {
    int key = p * 32 + (t >> 3);
    int dc = t & 7;                         // 16B chunk within row
    uint4 vv = *(const uint4*)(src + key * 64 + dc * 8);
    *(uint4*)((char*)Ls + key * 128 + ((dc ^ (key & 7)) * 16)) = vv;
  }
  __syncthreads();
  u16* dst = (u16*)(vT + (size_t)nh * HD * SEQ);
#pragma unroll
  for (int p = 0; p < 2; ++p) {
    int d = p * 32 + (t >> 3);
    int kc = t & 7;                         // key chunk (8 keys)
    union { u16 s[8]; uint4 v4; } u;
#pragma unroll
    for (int j = 0; j < 8; ++j) {
      int key = kc * 8 + j;
      u.s[j] = *(const u16*)((const char*)Ls + key * 128 + (((d >> 3) ^ (key & 7)) * 16) + (d & 7) * 2);
    }
    *(uint4*)(dst + (size_t)d * SEQ + kt * 64 + kc * 8) = u.v4;
  }
}

// ---------------- flash attention ----------------
// Q is pre-scaled by (1/sqrt(EMB))*log2(e) so softmax runs in exp2 domain.
__global__ __launch_bounds__(256) void attn_k(const __hip_bfloat16* __restrict__ qp,
                                              const __hip_bfloat16* __restrict__ kp,
                                              const __hip_bfloat16* __restrict__ vT,
                                              const u64* __restrict__ mbits,
                                              __hip_bfloat16* __restrict__ obuf) {
  __shared__ __align__(16) __hip_bfloat16 Kt[64 * 64];       // [key][kdim] swizzled
  __shared__ __align__(16) __hip_bfloat16 Vt[64 * 64];       // [d][key]   swizzled
  __shared__ __align__(16) __hip_bfloat16 Pl[4][16 * 64];    // per-wave P strip, swizzled
  int t = threadIdx.x, lane = t & 63, w = t >> 6;
  int qb = blockIdx.x;
  int nh = blockIdx.y;
  int n = nh >> 4, h = nh & 15;
  const __hip_bfloat16* Qg = qp + ((size_t)nh * SEQ + qb * 64) * HD;
  const char* Kg = (const char*)(kp + (size_t)nh * SEQ * HD);
  const char* Vg = (const char*)(vT + (size_t)nh * HD * SEQ);
  int l15 = lane & 15, l4 = lane >> 4;

  int srow = t >> 3;
  int schunk = (t & 7) ^ (srow & 7);
  int soffA = srow * 128 + schunk * 16;

  bf16x8 qf[2];
#pragma unroll
  for (int c = 0; c < 2; ++c)
    qf[c] = *(const bf16x8*)(Qg + (size_t)(w * 16 + l15) * HD + c * 32 + l4 * 8);

  const bf16x8 ones = {(short)0x3F80, (short)0x3F80, (short)0x3F80, (short)0x3F80,
                       (short)0x3F80, (short)0x3F80, (short)0x3F80, (short)0x3F80};

  f32x4 of[4];
#pragma unroll
  for (int dt = 0; dt < 4; ++dt)
#pragma unroll
    for (int j = 0; j < 4; ++j) of[dt][j] = 0.f;
  float mrow[4], lrow[4];
#pragma unroll
  for (int r = 0; r < 4; ++r) { mrow[r] = -1e20f; lrow[r] = 0.f; }

  int q0 = qb * 64 + w * 16 + l4 * 4;
  const u64* mb = mbits + (size_t)n * 32 * 2048 + q0;

  for (int kt = 0; kt < SEQ / 64; ++kt) {
    __syncthreads();
    {
      const char* gk = Kg + (size_t)kt * 8192;
      char* lk = (char*)Kt + w * 1024;
      load_lds_16B(gk + soffA, lk);
      load_lds_16B(gk + soffA + 4096, lk + 4096);   // rows+32: same XOR since (r+32)&7==r&7
      const char* gv = Vg + (size_t)kt * 128;
      char* lv = (char*)Vt + w * 1024;
      load_lds_16B(gv + (size_t)srow * 4096 + (size_t)schunk * 16, lv);
      load_lds_16B(gv + (size_t)(srow + 32) * 4096 + (size_t)schunk * 16, lv + 4096);
    }
    // mask words for this tile (32B contiguous, L2-hot broadcast)
    ulonglong2 mwa = *(const ulonglong2*)(mb + (size_t)kt * 2048);
    ulonglong2 mwb = *(const ulonglong2*)(mb + (size_t)kt * 2048 + 2);
    asm volatile("s_waitcnt vmcnt(0)" ::: "memory");
    __syncthreads();

    // ---- S = Q K^T (already in exp2 domain)
    f32x4 sf[4];
#pragma unroll
    for (int ct = 0; ct < 4; ++ct)
#pragma unroll
      for (int j = 0; j < 4; ++j) sf[ct][j] = 0.f;
#pragma unroll
    for (int c = 0; c < 2; ++c) {
#pragma unroll
      for (int ct = 0; ct < 4; ++ct) {
        int krow = ct * 16 + l15;
        bf16x8 bk = *(const bf16x8*)((const char*)Kt + krow * 128 + (((c * 4 + l4) ^ (l15 & 7)) * 16));
        sf[ct] = __builtin_amdgcn_mfma_f32_16x16x32_bf16(qf[c], bk, sf[ct], 0, 0, 0);
      }
    }

    // ---- online softmax, max over unmasked superset (exact; mn >= true max)
    float tmax[4];
#pragma unroll
    for (int r = 0; r < 4; ++r)
      tmax[r] = fmaxf(fmaxf(sf[0][r], sf[1][r]), fmaxf(sf[2][r], sf[3][r]));
    bool need = (tmax[0] > mrow[0]) || (tmax[1] > mrow[1]) ||
                (tmax[2] > mrow[2]) || (tmax[3] > mrow[3]);
    if (__any(need)) {
#pragma unroll
      for (int off = 1; off < 16; off <<= 1)
#pragma unroll
        for (int r = 0; r < 4; ++r)
          tmax[r] = fmaxf(tmax[r], __shfl_xor(tmax[r], off, 16));
#pragma unroll
      for (int r = 0; r < 4; ++r) {
        float mn = fmaxf(mrow[r], tmax[r]);
        float corr = __builtin_amdgcn_exp2f(mrow[r] - mn);
        mrow[r] = mn;
        lrow[r] *= corr;
#pragma unroll
        for (int dt = 0; dt < 4; ++dt) of[dt][r] *= corr;
      }
    }
    // ---- p = exp2(s - m), then mask-zero (bit ct*16+l15 of row word)
    u64 mw[4] = {mwa.x, mwa.y, mwb.x, mwb.y};
#pragma unroll
    for (int r = 0; r < 4; ++r) {
      u32 slo = ((u32)mw[r]) >> l15;
      u32 shi = ((u32)(mw[r] >> 32)) >> l15;
      float p0 = __builtin_amdgcn_exp2f(sf[0][r] - mrow[r]);
      float p1 = __builtin_amdgcn_exp2f(sf[1][r] - mrow[r]);
      float p2 = __builtin_amdgcn_exp2f(sf[2][r] - mrow[r]);
      float p3 = __builtin_amdgcn_exp2f(sf[3][r] - mrow[r]);
      sf[0][r] = (slo & 1u) ? p0 : 0.f;
      sf[1][r] = (slo & 0x10000u) ? p1 : 0.f;
      sf[2][r] = (shi & 1u) ? p2 : 0.f;
      sf[3][r] = (shi & 0x10000u) ? p3 : 0.f;
    }
    // ---- P -> LDS strip (swizzled)
#pragma unroll
    for (int ct = 0; ct < 4; ++ct)
#pragma unroll
      for (int r = 0; r < 4; ++r) {
        int prow = l4 * 4 + r;
        int pchunk = (ct * 2 + (l15 >> 3)) ^ (prow & 7);
        *(__hip_bfloat16*)((char*)&Pl[w][0] + prow * 128 + pchunk * 16 + (l15 & 7) * 2) =
            __float2bfloat16(sf[ct][r]);
      }
    // ---- row-sum via MFMA (P . ones), then PV
    bf16x8 pa[2];
#pragma unroll
    for (int kc = 0; kc < 2; ++kc)
      pa[kc] = *(const bf16x8*)((const char*)&Pl[w][0] + l15 * 128 + (((kc * 4 + l4) ^ (l15 & 7)) * 16));
    f32x4 rsum4 = {0.f, 0.f, 0.f, 0.f};
    rsum4 = __builtin_amdgcn_mfma_f32_16x16x32_bf16(pa[0], ones, rsum4, 0, 0, 0);
    rsum4 = __builtin_amdgcn_mfma_f32_16x16x32_bf16(pa[1], ones, rsum4, 0, 0, 0);
#pragma unroll
    for (int r = 0; r < 4; ++r) lrow[r] += rsum4[r];
#pragma unroll
    for (int kc = 0; kc < 2; ++kc) {
#pragma unroll
      for (int dt = 0; dt < 4; ++dt) {
        int vrow = dt * 16 + l15;
        bf16x8 bv = *(const bf16x8*)((const char*)Vt + vrow * 128 + (((kc * 4 + l4) ^ (l15 & 7)) * 16));
        of[dt] = __builtin_amdgcn_mfma_f32_16x16x32_bf16(pa[kc], bv, of[dt], 0, 0, 0);
      }
    }
  }
#pragma unroll
  for (int r = 0; r < 4; ++r) lrow[r] = 1.f / lrow[r];
  size_t orow0 = (size_t)n * SEQ + qb * 64 + w * 16 + l4 * 4;
#pragma unroll
  for (int dt = 0; dt < 4; ++dt)
#pragma unroll
    for (int r = 0; r < 4; ++r) {
      float v = of[dt][r] * lrow[r];
      obuf[(orow0 + r) * EMB + h * HD + dt * 16 + l15] = __float2bfloat16(v);
    }
}

// ---------------- output GEMM ----------------
__global__ __launch_bounds__(256) void out_gemm_k(const __hip_bfloat16* __restrict__ A,
                                                  const __hip_bfloat16* __restrict__ Bw,
                                                  const float* __restrict__ bias,
                                                  float* __restrict__ Y) {
  __shared__ __align__(16) __hip_bfloat16 As[128 * 32];
  __shared__ __align__(16) __hip_bfloat16 Bs[128 * 32];
  int t = threadIdx.x, lane = t & 63, w = t >> 6;
  int l15 = lane & 15, l4 = lane >> 4;
  int bm = blockIdx.x * 128, bn = blockIdx.y * 128;
  int wr = w >> 1, wc = w & 1;
  f32x4 acc[4][4];
#pragma unroll
  for (int m = 0; m < 4; ++m)
#pragma unroll
    for (int nn = 0; nn < 4; ++nn)
#pragma unroll
      for (int j = 0; j < 4; ++j) acc[m][nn][j] = 0.f;

  int o = t * 8;
  int srow = o >> 5, scol = o & 31;
  for (int kt = 0; kt < 32; ++kt) {
    __syncthreads();
    {
      const char* ga = (const char*)(A + (size_t)(bm + srow) * 1024 + kt * 32 + scol);
      char* la = (char*)As + w * 1024;
      load_lds_16B(ga, la);
      load_lds_16B((const char*)(A + (size_t)(bm + srow + 64) * 1024 + kt * 32 + scol), la + 4096);
      const char* gb = (const char*)(Bw + (size_t)(bn + srow) * 1024 + kt * 32 + scol);
      char* lb = (char*)Bs + w * 1024;
      load_lds_16B(gb, lb);
      load_lds_16B((const char*)(Bw + (size_t)(bn + srow + 64) * 1024 + kt * 32 + scol), lb + 4096);
    }
    asm volatile("s_waitcnt vmcnt(0)" ::: "memory");
    __syncthreads();
    bf16x8 af[4], bfr[4];
#pragma unroll
    for (int m = 0; m < 4; ++m)
      af[m] = *(const bf16x8*)((const char*)As + (wr * 64 + m * 16 + l15) * 64 + l4 * 16);
#pragma unroll
    for (int nn = 0; nn < 4; ++nn)
      bfr[nn] = *(const bf16x8*)((const char*)Bs + (wc * 64 + nn * 16 + l15) * 64 + l4 * 16);
#pragma unroll
    for (int m = 0; m < 4; ++m)
#pragma unroll
      for (int nn = 0; nn < 4; ++nn)
        acc[m][nn] = __builtin_amdgcn_mfma_f32_16x16x32_bf16(af[m], bfr[nn], acc[m][nn], 0, 0, 0);
  }
#pragma unroll
  for (int m = 0; m < 4; ++m)
#pragma unroll
    for (int nn = 0; nn < 4; ++nn)
#pragma unroll
      for (int r = 0; r < 4; ++r) {
        int row = bm + wr * 64 + m * 16 + l4 * 4 + r;
        int col = bn + wc * 64 + nn * 16 + l15;
        Y[(size_t)row * 1024 + col] = acc[m][nn][r] + bias[col];
      }
}

extern "C" void kernel_launch(void* const* d_in, const int* in_sizes, int n_in,
                              void* d_out, int out_size, void* d_ws, size_t ws_size,
                              hipStream_t stream) {
  const float* values  = (const float*)d_in[0];
  const float* keys    = (const float*)d_in[1];
  const float* queries = (const float*)d_in[2];
  const int*   mask    = (const int*)d_in[3];
  const float* Wv      = (const float*)d_in[4];
  const float* Wk      = (const float*)d_in[5];
  const float* Wq      = (const float*)d_in[6];
  const float* Wo      = (const float*)d_in[7];
  const float* bo      = (const float*)d_in[8];
  float* out = (float*)d_out;

  char* ws = (char*)d_ws;
  __hip_bfloat16* qp   = (__hip_bfloat16*)(ws);
  __hip_bfloat16* kp   = (__hip_bfloat16*)(ws + (size_t)16 * 1024 * 1024);
  __hip_bfloat16* vp   = (__hip_bfloat16*)(ws + (size_t)32 * 1024 * 1024);
  __hip_bfloat16* obuf = (__hip_bfloat16*)(ws + (size_t)48 * 1024 * 1024);
  u64*            mbts = (u64*)           (ws + (size_t)64 * 1024 * 1024);
  __hip_bfloat16* wob  = (__hip_bfloat16*)(ws + (size_t)66 * 1024 * 1024);
  __hip_bfloat16* vTp  = (__hip_bfloat16*)(ws + (size_t)80 * 1024 * 1024);

  // Q pre-scale: (1/sqrt(EMB)) * log2(e) so attn softmax runs in exp2 domain
  const float qscale = 0.03125f * 1.44269504088896340736f;

  pack_mask_k<<<dim3(N_B * SEQ), 256, 0, stream>>>(mask, mbts);
  project_k<<<dim3(N_B * SEQ), 256, 0, stream>>>(queries, Wq, qp, qscale);
  project_k<<<dim3(N_B * SEQ), 256, 0, stream>>>(keys, Wk, kp, 1.0f);
  project_k<<<dim3(N_B * SEQ), 256, 0, stream>>>(values, Wv, vp, 1.0f);
  transpose_v_k<<<dim3(SEQ / 64, N_B * NH), 256, 0, stream>>>(vp, vTp);
  cvt_bf16_k<<<dim3(1024), 256, 0, stream>>>(Wo, wob);
  attn_k<<<dim3(SEQ / 64, N_B * NH), 256, 0, stream>>>(qp, kp, vTp, mbts, obuf);
  out_gemm_k<<<dim3(64, 8), 256, 0, stream>>>(obuf, wob, bo, out);
}

// Round 4
// 278.509 us; speedup vs baseline: 1.6397x; 1.1676x over previous
//
#include <hip/hip_runtime.h>
#include <hip/hip_bf16.h>

#define N_B 4
#define SEQ 2048
#define EMB 1024
#define NH  16
#define HD  64

typedef __attribute__((ext_vector_type(8))) short bf16x8;   // 8 bf16 in 4 VGPRs
typedef __attribute__((ext_vector_type(4))) float f32x4;
typedef unsigned int u32;
typedef unsigned long long u64;
typedef unsigned short u16;

__device__ __forceinline__ void load_lds_16B(const void* g, void* lds) {
  __builtin_amdgcn_global_load_lds(
      (const __attribute__((address_space(1))) u32*)g,
      (__attribute__((address_space(3))) u32*)lds, 16, 0, 0);
}

__device__ __forceinline__ u16 bf16bits(float x) {
  __hip_bfloat16 h = __float2bfloat16(x);
  return *(u16*)&h;
}

// ---------------- mask -> bitmask, layout [n][kb][q] (contiguous in q) ----------------
__global__ __launch_bounds__(256) void pack_mask_k(const int* __restrict__ mask,
                                                   u64* __restrict__ bits) {
  int row = blockIdx.x;                // n*SEQ + q
  int n = row >> 11, q = row & 2047;
  int lane = threadIdx.x & 63;
  int wv = threadIdx.x >> 6;
  const int* m = mask + (size_t)row * SEQ;
  for (int w = wv; w < SEQ / 64; w += 4) {
    int v = m[w * 64 + lane];
    u64 bal = __ballot(v != 0);
    if (lane == 0) bits[((size_t)n * 32 + w) * 2048 + q] = bal;
  }
}

// ---------------- per-head projection (optional output scale) ----------------
__global__ __launch_bounds__(256) void project_k(const float* __restrict__ x,
                                                 const float* __restrict__ W,
                                                 __hip_bfloat16* __restrict__ out,
                                                 float scale) {
  __shared__ __align__(16) float Ws4[64 * 17 * 4];  // W rows as float4, padded: [d][17]
  __shared__ __align__(16) float xs[1024];
  int t = threadIdx.x;
  int row = blockIdx.x;            // n*SEQ + l
  int n = row >> 11, l = row & 2047;
  const float4* W4 = (const float4*)W;
#pragma unroll
  for (int i = 0; i < 4; ++i) {
    int f4 = i * 256 + t;                 // f4 = d*16 + dd4
    int d = f4 >> 4, dd4 = f4 & 15;
    *(float4*)&Ws4[(d * 17 + dd4) * 4] = W4[f4];
  }
  float4 v = ((const float4*)(x + (size_t)row * EMB))[t];
  *(float4*)&xs[t * 4] = v;
  __syncthreads();
  int d = t & 63, wv = t >> 6;
  float s[4] = {0.f, 0.f, 0.f, 0.f};
#pragma unroll
  for (int dd4 = 0; dd4 < 16; ++dd4) {
    float4 wv4 = *(const float4*)&Ws4[(d * 17 + dd4) * 4];
#pragma unroll
    for (int i = 0; i < 4; ++i) {
      float4 xv = *(const float4*)&xs[(i * 4 + wv) * 64 + dd4 * 4];
      s[i] += xv.x * wv4.x + xv.y * wv4.y + xv.z * wv4.z + xv.w * wv4.w;
    }
  }
#pragma unroll
  for (int i = 0; i < 4; ++i) {
    int h = i * 4 + wv;
    out[((size_t)(n * NH + h) * SEQ + l) * HD + d] = __float2bfloat16(s[i] * scale);
  }
}

// ---------------- fp32 -> bf16 copy (Wo) ----------------
__global__ __launch_bounds__(256) void cvt_bf16_k(const float* __restrict__ in,
                                                  __hip_bfloat16* __restrict__ out) {
  int i = (blockIdx.x * 256 + threadIdx.x) * 4;
  float4 v = *(const float4*)(in + i);
  out[i + 0] = __float2bfloat16(v.x);
  out[i + 1] = __float2bfloat16(v.y);
  out[i + 2] = __float2bfloat16(v.z);
  out[i + 3] = __float2bfloat16(v.w);
}

// ---------------- V transpose: vp[nh][key][d] -> vT[nh][d][key] ----------------
__global__ __launch_bounds__(256) void transpose_v_k(const __hip_bfloat16* __restrict__ vp,
                                                     __hip_bfloat16* __restrict__ vT) {
  __shared__ __align__(16) u16 Ls[64 * 64];   // [key][d], XOR-swizzled 16B chunks
  int t = threadIdx.x;
  int kt = blockIdx.x, nh = blockIdx.y;
  const u16* src = (const u16*)(vp + ((size_t)nh * SEQ + kt * 64) * HD);
#pragma unroll
  for (int p = 0; p < 2; ++p) {
    int key = p * 32 + (t >> 3);
    int dc = t & 7;                         // 16B chunk within row
    uint4 vv = *(const uint4*)(src + key * 64 + dc * 8);
    *(uint4*)((char*)Ls + key * 128 + ((dc ^ (key & 7)) * 16)) = vv;
  }
  __syncthreads();
  u16* dst = (u16*)(vT + (size_t)nh * HD * SEQ);
#pragma unroll
  for (int p = 0; p < 2; ++p) {
    int d = p * 32 + (t >> 3);
    int kc = t & 7;                         // key chunk (8 keys)
    union { u16 s[8]; uint4 v4; } u;
#pragma unroll
    for (int j = 0; j < 8; ++j) {
      int key = kc * 8 + j;
      u.s[j] = *(const u16*)((const char*)Ls + key * 128 + (((d >> 3) ^ (key & 7)) * 16) + (d & 7) * 2);
    }
    *(uint4*)(dst + (size_t)d * SEQ + kt * 64 + kc * 8) = u.v4;
  }
}

// ---------------- flash attention (swapped-operand S^T layout) ----------------
// Q pre-scaled by (1/sqrt(EMB))*log2(e). Each lane owns q = qb*64 + w*16 + l15.
// sf = mfma(K_frag, Q_frag) -> S^T: lane holds keys 16ct + l4*4 + r for its q.
// P strips reuse Kt space after QK (barrier C). LDS total = 16 KB -> 4 blocks/CU.
__global__ __launch_bounds__(256) void attn_k(const __hip_bfloat16* __restrict__ qp,
                                              const __hip_bfloat16* __restrict__ kp,
                                              const __hip_bfloat16* __restrict__ vT,
                                              const u64* __restrict__ mbits,
                                              __hip_bfloat16* __restrict__ obuf) {
  __shared__ __align__(16) __hip_bfloat16 Kt[64 * 64];       // [key][kdim] swz; P strip after QK
  __shared__ __align__(16) __hip_bfloat16 Vt[64 * 64];       // [d][key]   swz
  int t = threadIdx.x, lane = t & 63, w = t >> 6;
  int qb = blockIdx.x;
  int nh = blockIdx.y;
  int n = nh >> 4, h = nh & 15;
  const __hip_bfloat16* Qg = qp + ((size_t)nh * SEQ + qb * 64) * HD;
  const char* Kg = (const char*)(kp + (size_t)nh * SEQ * HD);
  const char* Vg = (const char*)(vT + (size_t)nh * HD * SEQ);
  int l15 = lane & 15, l4 = lane >> 4;
  int e7 = l15 & 7;

  int srow = t >> 3;
  int schunk = (t & 7) ^ (srow & 7);
  int soffA = srow * 128 + schunk * 16;

  // Q B-frag: col=l15 (q=w*16+l15), k = 32c + l4*8 + j  (same bytes as old A-frag load)
  bf16x8 qf[2];
#pragma unroll
  for (int c = 0; c < 2; ++c)
    qf[c] = *(const bf16x8*)(Qg + (size_t)(w * 16 + l15) * HD + c * 32 + l4 * 8);

  const bf16x8 ones = {(short)0x3F80, (short)0x3F80, (short)0x3F80, (short)0x3F80,
                       (short)0x3F80, (short)0x3F80, (short)0x3F80, (short)0x3F80};

  f32x4 of[4];
#pragma unroll
  for (int dt = 0; dt < 4; ++dt)
#pragma unroll
    for (int j = 0; j < 4; ++j) of[dt][j] = 0.f;
  float mrow = -1e20f, lrow = 0.f;

  int q = qb * 64 + w * 16 + l15;
  const u64* mb = mbits + (size_t)n * 32 * 2048 + q;

  // hoisted LDS byte offsets
  int prow_b = (w * 16 + l15) * 128;            // wave-exclusive P strip rows
  int pw[4], pr[2];
#pragma unroll
  for (int ct = 0; ct < 4; ++ct)
    pw[ct] = prow_b + (((2 * ct + (l4 >> 1)) ^ e7) * 16) + (l4 & 1) * 8;
#pragma unroll
  for (int kc = 0; kc < 2; ++kc)
    pr[kc] = prow_b + (((4 * kc + l4) ^ e7) * 16);

  for (int kt = 0; kt < SEQ / 64; ++kt) {
    __syncthreads();                             // A: prev-iter LDS reads done
    {
      const char* gk = Kg + (size_t)kt * 8192;
      char* lk = (char*)Kt + w * 1024;
      load_lds_16B(gk + soffA, lk);
      load_lds_16B(gk + soffA + 4096, lk + 4096);
      const char* gv = Vg + (size_t)kt * 128;
      char* lv = (char*)Vt + w * 1024;
      load_lds_16B(gv + (size_t)srow * 4096 + (size_t)schunk * 16, lv);
      load_lds_16B(gv + (size_t)(srow + 32) * 4096 + (size_t)schunk * 16, lv + 4096);
    }
    u64 mw = mb[(size_t)kt * 2048];              // 1 word per lane (its q)
    asm volatile("s_waitcnt vmcnt(0)" ::: "memory");
    __syncthreads();                             // B: tiles staged

    // ---- S^T = K Q^T: A = K-frag (rows=keys), B = Q-frag (cols=q)
    f32x4 sf[4];
#pragma unroll
    for (int ct = 0; ct < 4; ++ct)
#pragma unroll
      for (int j = 0; j < 4; ++j) sf[ct][j] = 0.f;
#pragma unroll
    for (int c = 0; c < 2; ++c) {
#pragma unroll
      for (int ct = 0; ct < 4; ++ct) {
        int krow = ct * 16 + l15;
        bf16x8 ak = *(const bf16x8*)((const char*)Kt + krow * 128 + (((c * 4 + l4) ^ e7) * 16));
        sf[ct] = __builtin_amdgcn_mfma_f32_16x16x32_bf16(ak, qf[c], sf[ct], 0, 0, 0);
      }
    }

    // ---- online softmax (scalar per lane; max over unmasked superset, exact)
    float tmax = sf[0][0];
#pragma unroll
    for (int ct = 0; ct < 4; ++ct)
#pragma unroll
      for (int r = 0; r < 4; ++r) tmax = fmaxf(tmax, sf[ct][r]);
    if (__any(tmax > mrow)) {
      float tm = tmax;
      tm = fmaxf(tm, __shfl_xor(tm, 16));
      tm = fmaxf(tm, __shfl_xor(tm, 32));
      float mn = fmaxf(mrow, tm);
      float corr = __builtin_amdgcn_exp2f(mrow - mn);
      mrow = mn;
      lrow *= corr;
#pragma unroll
      for (int dt = 0; dt < 4; ++dt)
#pragma unroll
        for (int r = 0; r < 4; ++r) of[dt][r] *= corr;
    }
    // ---- p = exp2(s - m), mask-zero (bit 16ct + 4*l4 + r of mw)
    u64 m4 = mw >> (l4 * 4);
    u32 c0 = (u32)m4, c1 = (u32)(m4 >> 32);
    float p[4][4];
#pragma unroll
    for (int ct = 0; ct < 4; ++ct) {
      u32 sel = (ct & 2) ? c1 : c0;
      u32 base = (ct & 1) ? 0x10000u : 1u;
#pragma unroll
      for (int r = 0; r < 4; ++r) {
        float e = __builtin_amdgcn_exp2f(sf[ct][r] - mrow);
        p[ct][r] = (sel & (base << r)) ? e : 0.f;
      }
    }
    __syncthreads();                             // C: all QK reads of Kt complete
    // ---- pack P (bf16 pairs) into own Kt strip: 4 x ds_write_b64
#pragma unroll
    for (int ct = 0; ct < 4; ++ct) {
      u32 lo = (u32)bf16bits(p[ct][0]) | ((u32)bf16bits(p[ct][1]) << 16);
      u32 hi = (u32)bf16bits(p[ct][2]) | ((u32)bf16bits(p[ct][3]) << 16);
      uint2 v2 = {lo, hi};
      *(uint2*)((char*)Kt + pw[ct]) = v2;
    }
    // ---- B-frags for PV + row-sum via MFMA
    bf16x8 pb[2];
#pragma unroll
    for (int kc = 0; kc < 2; ++kc)
      pb[kc] = *(const bf16x8*)((const char*)Kt + pr[kc]);
    f32x4 rs = {0.f, 0.f, 0.f, 0.f};
    rs = __builtin_amdgcn_mfma_f32_16x16x32_bf16(ones, pb[0], rs, 0, 0, 0);
    rs = __builtin_amdgcn_mfma_f32_16x16x32_bf16(ones, pb[1], rs, 0, 0, 0);
    lrow += rs[0];
    // ---- O^T += V^T P : A = V^T-frag (rows=d), B = P-frag (cols=q)
#pragma unroll
    for (int kc = 0; kc < 2; ++kc) {
#pragma unroll
      for (int dt = 0; dt < 4; ++dt) {
        int vrow = dt * 16 + l15;
        bf16x8 av = *(const bf16x8*)((const char*)Vt + vrow * 128 + (((kc * 4 + l4) ^ e7) * 16));
        of[dt] = __builtin_amdgcn_mfma_f32_16x16x32_bf16(av, pb[kc], of[dt], 0, 0, 0);
      }
    }
  }
  // ---- epilogue: lane owns q; d = 16dt + 4*l4 + r (r-consecutive -> 8B stores)
  float inv = 1.f / lrow;
  size_t obase = ((size_t)n * SEQ + q) * EMB + h * HD;
#pragma unroll
  for (int dt = 0; dt < 4; ++dt) {
    u32 lo = (u32)bf16bits(of[dt][0] * inv) | ((u32)bf16bits(of[dt][1] * inv) << 16);
    u32 hi = (u32)bf16bits(of[dt][2] * inv) | ((u32)bf16bits(of[dt][3] * inv) << 16);
    uint2 v2 = {lo, hi};
    *(uint2*)(obuf + obase + dt * 16 + l4 * 4) = v2;
  }
}

// ---------------- output GEMM ----------------
__global__ __launch_bounds__(256) void out_gemm_k(const __hip_bfloat16* __restrict__ A,
                                                  const __hip_bfloat16* __restrict__ Bw,
                                                  const float* __restrict__ bias,
                                                  float* __restrict__ Y) {
  __shared__ __align__(16) __hip_bfloat16 As[128 * 32];
  __shared__ __align__(16) __hip_bfloat16 Bs[128 * 32];
  int t = threadIdx.x, lane = t & 63, w = t >> 6;
  int l15 = lane & 15, l4 = lane >> 4;
  int bm = blockIdx.x * 128, bn = blockIdx.y * 128;
  int wr = w >> 1, wc = w & 1;
  f32x4 acc[4][4];
#pragma unroll
  for (int m = 0; m < 4; ++m)
#pragma unroll
    for (int nn = 0; nn < 4; ++nn)
#pragma unroll
      for (int j = 0; j < 4; ++j) acc[m][nn][j] = 0.f;

  int o = t * 8;
  int srow = o >> 5, scol = o & 31;
  for (int kt = 0; kt < 32; ++kt) {
    __syncthreads();
    {
      const char* ga = (const char*)(A + (size_t)(bm + srow) * 1024 + kt * 32 + scol);
      char* la = (char*)As + w * 1024;
      load_lds_16B(ga, la);
      load_lds_16B((const char*)(A + (size_t)(bm + srow + 64) * 1024 + kt * 32 + scol), la + 4096);
      const char* gb = (const char*)(Bw + (size_t)(bn + srow) * 1024 + kt * 32 + scol);
      char* lb = (char*)Bs + w * 1024;
      load_lds_16B(gb, lb);
      load_lds_16B((const char*)(Bw + (size_t)(bn + srow + 64) * 1024 + kt * 32 + scol), lb + 4096);
    }
    asm volatile("s_waitcnt vmcnt(0)" ::: "memory");
    __syncthreads();
    bf16x8 af[4], bfr[4];
#pragma unroll
    for (int m = 0; m < 4; ++m)
      af[m] = *(const bf16x8*)((const char*)As + (wr * 64 + m * 16 + l15) * 64 + l4 * 16);
#pragma unroll
    for (int nn = 0; nn < 4; ++nn)
      bfr[nn] = *(const bf16x8*)((const char*)Bs + (wc * 64 + nn * 16 + l15) * 64 + l4 * 16);
#pragma unroll
    for (int m = 0; m < 4; ++m)
#pragma unroll
      for (int nn = 0; nn < 4; ++nn)
        acc[m][nn] = __builtin_amdgcn_mfma_f32_16x16x32_bf16(af[m], bfr[nn], acc[m][nn], 0, 0, 0);
  }
#pragma unroll
  for (int m = 0; m < 4; ++m)
#pragma unroll
    for (int nn = 0; nn < 4; ++nn)
#pragma unroll
      for (int r = 0; r < 4; ++r) {
        int row = bm + wr * 64 + m * 16 + l4 * 4 + r;
        int col = bn + wc * 64 + nn * 16 + l15;
        Y[(size_t)row * 1024 + col] = acc[m][nn][r] + bias[col];
      }
}

extern "C" void kernel_launch(void* const* d_in, const int* in_sizes, int n_in,
                              void* d_out, int out_size, void* d_ws, size_t ws_size,
                              hipStream_t stream) {
  const float* values  = (const float*)d_in[0];
  const float* keys    = (const float*)d_in[1];
  const float* queries = (const float*)d_in[2];
  const int*   mask    = (const int*)d_in[3];
  const float* Wv      = (const float*)d_in[4];
  const float* Wk      = (const float*)d_in[5];
  const float* Wq      = (const float*)d_in[6];
  const float* Wo      = (const float*)d_in[7];
  const float* bo      = (const float*)d_in[8];
  float* out = (float*)d_out;

  char* ws = (char*)d_ws;
  __hip_bfloat16* qp   = (__hip_bfloat16*)(ws);
  __hip_bfloat16* kp   = (__hip_bfloat16*)(ws + (size_t)16 * 1024 * 1024);
  __hip_bfloat16* vp   = (__hip_bfloat16*)(ws + (size_t)32 * 1024 * 1024);
  __hip_bfloat16* obuf = (__hip_bfloat16*)(ws + (size_t)48 * 1024 * 1024);
  u64*            mbts = (u64*)           (ws + (size_t)64 * 1024 * 1024);
  __hip_bfloat16* wob  = (__hip_bfloat16*)(ws + (size_t)66 * 1024 * 1024);
  __hip_bfloat16* vTp  = (__hip_bfloat16*)(ws + (size_t)80 * 1024 * 1024);

  // Q pre-scale: (1/sqrt(EMB)) * log2(e) so attn softmax runs in exp2 domain
  const float qscale = 0.03125f * 1.44269504088896340736f;

  pack_mask_k<<<dim3(N_B * SEQ), 256, 0, stream>>>(mask, mbts);
  project_k<<<dim3(N_B * SEQ), 256, 0, stream>>>(queries, Wq, qp, qscale);
  project_k<<<dim3(N_B * SEQ), 256, 0, stream>>>(keys, Wk, kp, 1.0f);
  project_k<<<dim3(N_B * SEQ), 256, 0, stream>>>(values, Wv, vp, 1.0f);
  transpose_v_k<<<dim3(SEQ / 64, N_B * NH), 256, 0, stream>>>(vp, vTp);
  cvt_bf16_k<<<dim3(1024), 256, 0, stream>>>(Wo, wob);
  attn_k<<<dim3(SEQ / 64, N_B * NH), 256, 0, stream>>>(qp, kp, vTp, mbts, obuf);
  out_gemm_k<<<dim3(64, 8), 256, 0, stream>>>(obuf, wob, bo, out);
}